// Round 3
// baseline (169.873 us; speedup 1.0000x reference)
//
#include <hip/hip_runtime.h>
#include <math.h>

// NoisyTopkRouter, all-f32.
// x[ntok,384] @ {w_route,w_noise}[8,384]^T -> 16 logits/token,
// noisy = logit + noise*softplus(noise_logit), top-2 of 8, sparse softmax.
// Output: [ntok*8 probs f32 | ntok*2 indices-as-f32].
//
// R9: first run with kernel-attributed counters: 67us, 800 GB/s (10% peak),
// VALU 28%, LDS conflicts 0, Occupancy 43%. All pipes idle -> either
// uncontrollable (L3 dirty-drain from the poison fills / post-fill clock
// throttle) or TLP shortfall: occupancy was GRID-limited (1024 blocks =
// 4 blocks/CU x 4 waves = 16 waves/CU). R6 tested ILP depth (null); TLP
// was never tested. This round: 1 token per 8-lane group (was 2) ->
// 32 tokens/block, 2048 blocks -> LDS-capped 6 blocks/CU = 24 waves/CU
// (1.5x TLP). LDS instrs/token double but each ds_read_b128 is an 8-way
// broadcast (128B distinct) - stays under the HBM floor. VGPR ~55 (<=64).
// Prediction: Occupancy 43->~70. If TLP-limited: kernel 67->~45-50us,
// dur 162->~145-150. If null: composite roofline, declare next round.

constexpr int D = 384;

__device__ __forceinline__ float dpp_xor1(float v) {   // lane ^ 1, quad_perm [1,0,3,2]
    return __int_as_float(__builtin_amdgcn_update_dpp(
        0, __float_as_int(v), 0xB1, 0xF, 0xF, true));
}
__device__ __forceinline__ float dpp_xor2(float v) {   // lane ^ 2, quad_perm [2,3,0,1]
    return __int_as_float(__builtin_amdgcn_update_dpp(
        0, __float_as_int(v), 0x4E, 0xF, 0xF, true));
}
__device__ __forceinline__ float swz_xor4(float v) {   // ds_swizzle BitMode xor 4
    return __int_as_float(__builtin_amdgcn_ds_swizzle(__float_as_int(v), 0x101F));
}

__global__ __launch_bounds__(256, 4) void noisy_topk_router_f32(
    const float* __restrict__ x,        // [ntok,384]
    const float* __restrict__ noise,    // [ntok,8]
    const float* __restrict__ w_route,  // [8,384]
    const float* __restrict__ b_route,  // [8]
    const float* __restrict__ w_noise,  // [8,384]
    const float* __restrict__ b_noise,  // [8]
    float* __restrict__ out,            // [ntok*8 | ntok*2]
    int ntok)
{
    __shared__ float w_lds[16 * D];   // rows: e=0..7 route, e=8..15 noise
    __shared__ float bias[16];

    const int tid = threadIdx.x;

    // stage weights: 2 x 3072 floats = 2 x 768 float4; 256 threads x 3 each
#pragma unroll
    for (int r = 0; r < 3; ++r) {
        int i = (tid + 256 * r) * 4;                       // < 3072
        *(float4*)(w_lds + i)        = *(const float4*)(w_route + i);
        *(float4*)(w_lds + 3072 + i) = *(const float4*)(w_noise + i);
    }
    if (tid < 8)       bias[tid] = b_route[tid];
    else if (tid < 16) bias[tid] = b_noise[tid - 8];
    __syncthreads();

    const int wave = tid >> 6;
    const int lane = tid & 63;
    const int tg   = lane >> 3;       // token-group 0..7 (8 lanes each)
    const int c    = lane & 7;        // d-slice 0..7
    // group handles 1 token; wave covers 8; block covers 32
    const int token = blockIdx.x * 32 + wave * 8 + tg;

    float acc[16];
#pragma unroll
    for (int e = 0; e < 16; ++e) acc[e] = 0.f;

    // chunk q (0..11): lane c covers d = q*32 + c*4 .. +4
    const float* xr = x + (size_t)token * D + c * 4;

    float4 xa[3], xb[3];
#pragma unroll
    for (int qq = 0; qq < 3; ++qq)
        xa[qq] = *(const float4*)(xr + qq * 32);

#pragma unroll
    for (int s = 0; s < 4; ++s) {
        // prefetch next superstep (s=3: dummy re-read of chunk 0..2)
        const int qn = (s < 3) ? (s + 1) * 3 : 0;
#pragma unroll
        for (int qq = 0; qq < 3; ++qq)
            xb[qq] = *(const float4*)(xr + (qn + qq) * 32);
        // consume current superstep from registers
#pragma unroll
        for (int qq = 0; qq < 3; ++qq) {
            const int q = s * 3 + qq;
            const float* wj = w_lds + q * 32 + c * 4;
#pragma unroll
            for (int e = 0; e < 16; ++e) {
                float4 wv = *(const float4*)(wj + e * D);   // 8-way broadcast
                acc[e] += xa[qq].x * wv.x + xa[qq].y * wv.y
                        + xa[qq].z * wv.z + xa[qq].w * wv.w;
            }
        }
#pragma unroll
        for (int qq = 0; qq < 3; ++qq) xa[qq] = xb[qq];
    }

    // full butterfly reduction over the 8 d-slices:
    // xor1 (DPP) + xor2 (DPP) + xor4 (ds_swizzle); afterwards every lane
    // of the group holds the complete 384-sum for its token.
#pragma unroll
    for (int e = 0; e < 16; ++e) acc[e] += dpp_xor1(acc[e]);
#pragma unroll
    for (int e = 0; e < 16; ++e) acc[e] += dpp_xor2(acc[e]);
#pragma unroll
    for (int e = 0; e < 16; ++e) acc[e] += swz_xor4(acc[e]);

    if (c == 0) {
        float4 n0 = *(const float4*)(noise + (size_t)token * 8);
        float4 n1 = *(const float4*)(noise + (size_t)token * 8 + 4);
        float nz[8] = {n0.x, n0.y, n0.z, n0.w, n1.x, n1.y, n1.z, n1.w};

        float noisy[8];
#pragma unroll
        for (int e = 0; e < 8; ++e) {
            float lg = acc[e] + bias[e];
            float nl = acc[8 + e] + bias[8 + e];
            // stable softplus: max(z,0) + log1p(exp(-|z|))
            float sp = fmaxf(nl, 0.f) + log1pf(expf(-fabsf(nl)));
            noisy[e] = lg + nz[e] * sp;
        }

        // top-2, jax.lax.top_k tie-break: earliest index wins ties
        float v0 = noisy[0]; int i0 = 0;
#pragma unroll
        for (int e = 1; e < 8; ++e)
            if (noisy[e] > v0) { v0 = noisy[e]; i0 = e; }
        float v1 = -INFINITY; int i1 = 0;
#pragma unroll
        for (int e = 0; e < 8; ++e)
            if (e != i0 && noisy[e] > v1) { v1 = noisy[e]; i1 = e; }

        // 2-way softmax (other experts exactly 0)
        float ex  = expf(v1 - v0);       // v1 <= v0
        float inv = 1.f / (1.f + ex);
        float p0  = inv;
        float p1  = ex * inv;

        float pr[8];
#pragma unroll
        for (int e = 0; e < 8; ++e)
            pr[e] = (e == i0) ? p0 : ((e == i1) ? p1 : 0.f);

        float* orow = out + (size_t)token * 8;
        *(float4*)(orow)     = make_float4(pr[0], pr[1], pr[2], pr[3]);
        *(float4*)(orow + 4) = make_float4(pr[4], pr[5], pr[6], pr[7]);

        *(float2*)(out + (size_t)ntok * 8 + (size_t)token * 2) =
            make_float2((float)i0, (float)i1);
    }
}

extern "C" void kernel_launch(void* const* d_in, const int* in_sizes, int n_in,
                              void* d_out, int out_size, void* d_ws, size_t ws_size,
                              hipStream_t stream) {
    const float* x       = (const float*)d_in[0];
    const float* noise   = (const float*)d_in[1];
    const float* w_route = (const float*)d_in[2];
    const float* b_route = (const float*)d_in[3];
    const float* w_noise = (const float*)d_in[4];
    const float* b_noise = (const float*)d_in[5];
    float* out = (float*)d_out;

    const int ntok   = in_sizes[0] / D;   // 65536
    const int blocks = ntok / 32;         // 32 tokens per 256-thread block

    hipLaunchKernelGGL(noisy_topk_router_f32, dim3(blocks), dim3(256), 0, stream,
                       x, noise, w_route, b_route, w_noise, b_noise, out, ntok);
}